// Round 3
// baseline (184.906 us; speedup 1.0000x reference)
//
#include <hip/hip_runtime.h>
#include <hip/hip_bf16.h>
#include <math.h>

#define NB 16
#define NT 2048
#define ND 512
#define NH 64

typedef __attribute__((ext_vector_type(8))) short short8;
typedef __attribute__((ext_vector_type(4))) float float4v;

// ---------------------------------------------------------------------------
// mask dtype robustness: byte layout -> first int32 reads 0x01010101 (lengths
// >= T/2 so mask[0..3] all true); int32 layout -> 1; f32 layout -> 0x3F800000.
// ---------------------------------------------------------------------------
__device__ __forceinline__ bool mask_is_bytes(const int* m) {
    return m[0] == 0x01010101;
}
__device__ __forceinline__ bool mask_at(const int* m, bool bytes, int i) {
    if (bytes) return ((const unsigned char*)m)[i] != 0;
    return m[i] != 0;
}

__device__ __forceinline__ unsigned short f2bf(float x) {
    unsigned int u = __float_as_uint(x);
    u += 0x7fffu + ((u >> 16) & 1u);
    return (unsigned short)(u >> 16);
}

// readlane: wave-uniform broadcast of one lane's value (index may be runtime,
// must be wave-uniform).
__device__ __forceinline__ float rlane(float x, int j) {
    return __int_as_float(__builtin_amdgcn_readlane(__float_as_int(x), j));
}

// DPP row_shr:N with identity fill (no row_bcast on CDNA -- combine the four
// 16-lane row totals with readlane instead).
template <int CTRL>
__device__ __forceinline__ float updpp(float x, int identBits) {
    return __int_as_float(__builtin_amdgcn_update_dpp(
        identBits, __float_as_int(x), CTRL, 0xF, 0xF, false));
}
// wave-wide max: 4x row_shr scan (lanes 15/31/47/63 hold row maxes) + 4 readlane.
__device__ __forceinline__ float wave_max(float m) {
    const int NI = (int)0xFF800000u;  // -inf
    m = fmaxf(m, updpp<0x111>(m, NI));   // row_shr:1
    m = fmaxf(m, updpp<0x112>(m, NI));   // row_shr:2
    m = fmaxf(m, updpp<0x114>(m, NI));   // row_shr:4
    m = fmaxf(m, updpp<0x118>(m, NI));   // row_shr:8
    float a = rlane(m, 15), bb = rlane(m, 31);
    float c = rlane(m, 47), d  = rlane(m, 63);
    return fmaxf(fmaxf(a, bb), fmaxf(c, d));
}
// wave-wide sum, same structure (fixed deterministic tree).
__device__ __forceinline__ float wave_sum(float x) {
    x += updpp<0x111>(x, 0);
    x += updpp<0x112>(x, 0);
    x += updpp<0x114>(x, 0);
    x += updpp<0x118>(x, 0);
    return (rlane(x, 15) + rlane(x, 31)) + (rlane(x, 47) + rlane(x, 63));
}

// ---------------------------------------------------------------------------
// Kernel A (prep): blocks [0,128) transpose W2 fp32[k][n] -> bf16 W2t[n][k];
// blocks [128,256) compute P (E,px,py,pz) per token once per batch into Pg.
// Masked tokens get sentinel (-1e30,0,0,0): dot vs any valid query = -huge,
// never in a top-8, never >= th8.
// ---------------------------------------------------------------------------
__global__ void __launch_bounds__(256) prep_kernel(
        const float* __restrict__ tok, const int* __restrict__ mask,
        const float* __restrict__ W2, unsigned short* __restrict__ W2t,
        float4* __restrict__ Pg) {
    int i = blockIdx.x * 256 + threadIdx.x;
    if (i < ND * NH) {
        int n = i & (ND - 1), k = i >> 9;
        W2t[n * NH + k] = f2bf(W2[k * ND + n]);
    } else {
        int j = i - ND * NH;                    // 0 .. NB*NT-1
        const bool mb = mask_is_bytes(mask);
        float4 tv = ((const float4*)tok)[j];
        bool m = mask_at(mask, mb, j);
        float E = tv.x, Pt = tv.y, eta = tv.z, phi = tv.w;
        float px = Pt * cosf(phi);
        float py = Pt * sinf(phi);
        float pz = Pt * sinhf(fminf(fmaxf(eta, -20.f), 20.f));
        Pg[j] = m ? make_float4(E, px, py, pz)
                  : make_float4(-1e30f, 0.f, 0.f, 0.f);
    }
}

// ---------------------------------------------------------------------------
// Kernel B: TRANSPOSED scan. lane = candidate, wave = 8 queries.
// Each lane holds the ENTIRE batch candidate slice (32 float4 in VGPRs,
// stride-64 coalesced). Per query: broadcast 4 query components (4 readlane),
// per-lane top-8 med3 chain over its 32 candidates, then 8 rounds of
// DPP-wave-max + pop to extract th2/th4/th8, then exact-membership pass 2
// from the same registers, DPP sum-reduce, mass. Zero broadcast delivery.
// ---------------------------------------------------------------------------
__global__ void __launch_bounds__(512, 2) fused_topk_mass_mlp_kernel(
        const int* __restrict__ mask,
        const float* __restrict__ W1,
        const float* __restrict__ b1,
        const unsigned short* __restrict__ W2t,
        const float* __restrict__ b2,
        const float4* __restrict__ Pg,
        float* __restrict__ out) {
    __shared__ unsigned short hs[64][88];     // 11 KB
    __shared__ float mass_s[3][64];           // 768 B
    __shared__ int wcnt[8];

    const int b    = blockIdx.y;
    const int t0   = blockIdx.x * 64;
    const int tid  = threadIdx.x;
    const int lane = tid & 63;
    const int w    = tid >> 6;
    const bool mb  = mask_is_bytes(mask);
    const float NEGBIG = -3.402823466e38f;
    const float MZ = sqrtf(1e-8f);

    const bool blockValid = mask_at(mask, mb, b * NT + t0);

    if (blockValid) {
        // ---- count L via ballots ----
        int cnt = 0;
#pragma unroll
        for (int it = 0; it < 4; ++it) {
            int i = tid + it * 512;
            cnt += (int)__popcll(__ballot(mask_at(mask, mb, b * NT + i)));
        }
        if (lane == 0) wcnt[w] = cnt;
        __syncthreads();                               // B1
        int L = 0;
#pragma unroll
        for (int j = 0; j < 8; ++j) L += wcnt[j];
        const int RACT = (L + 63) >> 6;                // active reg-groups

        const float4* __restrict__ Pb = Pg + (size_t)b * NT;
        float4 pt = Pb[t0 + lane];                     // query source for readlane

        // ---- whole candidate slice -> VGPRs (coalesced, one time) ----
        float4 cr[32];
#pragma unroll
        for (int r = 0; r < 32; ++r) cr[r] = Pb[r * 64 + lane];

        // ---- per-query pipeline (q rolled: small code, regs reused) ----
#pragma unroll 1
        for (int q = 0; q < 8; ++q) {
            const int ql = w * 8 + q;                  // query row in block
            if (t0 + ql < L) {                         // wave-uniform (mask monotone)
                const float Eq  =  rlane(pt.x, ql);
                const float npx = -rlane(pt.y, ql);
                const float npy = -rlane(pt.z, ql);
                const float npz = -rlane(pt.w, ql);

                // pass 1: per-lane top-8 chain (sorted desc v0..v7)
                float v0 = NEGBIG, v1 = NEGBIG, v2 = NEGBIG, v3 = NEGBIG;
                float v4 = NEGBIG, v5 = NEGBIG, v6 = NEGBIG, v7 = NEGBIG;
#pragma unroll
                for (int r = 0; r < 32; ++r) {
                    if (r < RACT) {                    // wave-uniform skip
                        float d = Eq * cr[r].x;
                        d = __builtin_fmaf(npx, cr[r].y, d);
                        d = __builtin_fmaf(npy, cr[r].z, d);
                        d = __builtin_fmaf(npz, cr[r].w, d);
                        float n0 = fmaxf(v0, d);
                        float n1 = __builtin_amdgcn_fmed3f(d, v0, v1);
                        float n2 = __builtin_amdgcn_fmed3f(d, v1, v2);
                        float n3 = __builtin_amdgcn_fmed3f(d, v2, v3);
                        float n4 = __builtin_amdgcn_fmed3f(d, v3, v4);
                        float n5 = __builtin_amdgcn_fmed3f(d, v4, v5);
                        float n6 = __builtin_amdgcn_fmed3f(d, v5, v6);
                        float n7 = __builtin_amdgcn_fmed3f(d, v6, v7);
                        v0 = n0; v1 = n1; v2 = n2; v3 = n3;
                        v4 = n4; v5 = n5; v6 = n6; v7 = n7;
                    }
                }

                // extraction: 8 rounds of global max + pop-shift.
                // round i yields the i-th largest of the union (64-way merge
                // of sorted lists); th2/th4/th8 captured at rounds 2/4/8.
                float th2 = NEGBIG, th4 = NEGBIG, th8 = NEGBIG;
#pragma unroll
                for (int round = 1; round <= 8; ++round) {
                    float gm = wave_max(v0);
                    if (round == 2) th2 = gm;
                    if (round == 4) th4 = gm;
                    if (round == 8) th8 = gm;
                    if (round < 8) {
                        bool pop = (v0 == gm);
                        v0 = pop ? v1 : v0;
                        v1 = pop ? v2 : v1;
                        v2 = pop ? v3 : v2;
                        v3 = pop ? v4 : v3;
                        v4 = pop ? v5 : v4;
                        v5 = pop ? v6 : v5;
                        v6 = pop ? v7 : v6;
                        v7 = pop ? NEGBIG : v7;
                    }
                }

                // pass 2: exact membership from the same registers
                // (identical fmaf sequence -> bitwise-identical d).
                float s2x = 0.f, s2y = 0.f, s2z = 0.f, s2w = 0.f;
                float s4x = 0.f, s4y = 0.f, s4z = 0.f, s4w = 0.f;
                float s8x = 0.f, s8y = 0.f, s8z = 0.f, s8w = 0.f;
#pragma unroll
                for (int r = 0; r < 32; ++r) {
                    if (r < RACT) {
                        float d = Eq * cr[r].x;
                        d = __builtin_fmaf(npx, cr[r].y, d);
                        d = __builtin_fmaf(npy, cr[r].z, d);
                        d = __builtin_fmaf(npz, cr[r].w, d);
                        if (d >= th8) {
                            s8x += cr[r].x; s8y += cr[r].y;
                            s8z += cr[r].z; s8w += cr[r].w;
                            if (d >= th4) {
                                s4x += cr[r].x; s4y += cr[r].y;
                                s4z += cr[r].z; s4w += cr[r].w;
                                if (d >= th2) {
                                    s2x += cr[r].x; s2y += cr[r].y;
                                    s2z += cr[r].z; s2w += cr[r].w;
                                }
                            }
                        }
                    }
                }

                // reduce 12 partial sums across the wave (DPP + readlane)
                float t2x = wave_sum(s2x), t2y = wave_sum(s2y);
                float t2z = wave_sum(s2z), t2w = wave_sum(s2w);
                float t4x = wave_sum(s4x), t4y = wave_sum(s4y);
                float t4z = wave_sum(s4z), t4w = wave_sum(s4w);
                float t8x = wave_sum(s8x), t8y = wave_sum(s8y);
                float t8z = wave_sum(s8z), t8w = wave_sum(s8w);

                auto massf = [&](float sx, float sy, float sz, float sw) -> float {
                    float qq = sx * sx;
                    qq = __builtin_fmaf(-sy, sy, qq);
                    qq = __builtin_fmaf(-sz, sz, qq);
                    qq = __builtin_fmaf(-sw, sw, qq);
                    qq = fmaxf(qq, 0.f);
                    return sqrtf(qq + 1e-8f);
                };
                if (lane == 0) {
                    mass_s[0][ql] = massf(t2x, t2y, t2z, t2w);
                    mass_s[1][ql] = massf(t4x, t4y, t4z, t4w);
                    mass_s[2][ql] = massf(t8x, t8y, t8z, t8w);
                }
            } else {
                if (lane == 0) {
                    mass_s[0][ql] = MZ;
                    mass_s[1][ql] = MZ;
                    mass_s[2][ql] = MZ;
                }
            }
        }
    } else {
        if (tid < 64) {
            mass_s[0][tid] = MZ;
            mass_s[1][tid] = MZ;
            mass_s[2][tid] = MZ;
        }
    }
    __syncthreads();                                   // B5 (common)

    // ---- h = gelu(mass @ W1 + b1), bf16 -> LDS ----
    {
        const int tt = lane;
        const int hr = w;                  // wave-uniform -> W1/b1 scalar loads
        float q0 = mass_s[0][tt];
        float q1 = mass_s[1][tt];
        float q2 = mass_s[2][tt];
        unsigned short hv[8];
#pragma unroll
        for (int j = 0; j < 8; ++j) {
            int hh = hr * 8 + j;
            float pre = b1[hh];
            pre = __builtin_fmaf(q0, W1[hh], pre);
            pre = __builtin_fmaf(q1, W1[NH + hh], pre);
            pre = __builtin_fmaf(q2, W1[2 * NH + hh], pre);
            float g = 0.5f * pre * (1.0f + erff(pre * 0.70710678118654752f));
            hv[j] = f2bf(g);
        }
        *(short8*)&hs[tt][hr * 8] = *(const short8*)hv;
    }
    __syncthreads();                                   // B6

    // ---- MFMA: out[b*NT + t0 .. +63][0..511] = h @ W2 + b2 ----
    const int col   = lane & 15;
    const int quad  = lane >> 4;
    const int mhalf = w >> 2;              // token half (0..1)
    const int nBase = (w & 3) * 128;

    short8 afrag[2][2];
#pragma unroll
    for (int mt = 0; mt < 2; ++mt)
#pragma unroll
        for (int ks = 0; ks < 2; ++ks)
            afrag[mt][ks] = *(const short8*)&hs[mhalf * 32 + mt * 16 + col][ks * 32 + quad * 8];

    float4v acc[2][8];
#pragma unroll
    for (int mt = 0; mt < 2; ++mt)
#pragma unroll
        for (int nt = 0; nt < 8; ++nt)
            acc[mt][nt] = (float4v)(0.f);

#pragma unroll
    for (int nt = 0; nt < 8; ++nt) {
        const unsigned short* wp = W2t + (nBase + nt * 16 + col) * NH + quad * 8;
        short8 bf0 = *(const short8*)(wp);
        short8 bf1 = *(const short8*)(wp + 32);
        acc[0][nt] = __builtin_amdgcn_mfma_f32_16x16x32_bf16(afrag[0][0], bf0, acc[0][nt], 0, 0, 0);
        acc[1][nt] = __builtin_amdgcn_mfma_f32_16x16x32_bf16(afrag[1][0], bf0, acc[1][nt], 0, 0, 0);
        acc[0][nt] = __builtin_amdgcn_mfma_f32_16x16x32_bf16(afrag[0][1], bf1, acc[0][nt], 0, 0, 0);
        acc[1][nt] = __builtin_amdgcn_mfma_f32_16x16x32_bf16(afrag[1][1], bf1, acc[1][nt], 0, 0, 0);
    }

#pragma unroll
    for (int nt = 0; nt < 8; ++nt) {
        float bias = b2[nBase + nt * 16 + col];
#pragma unroll
        for (int mt = 0; mt < 2; ++mt) {
            int mRow = b * NT + t0 + mhalf * 32 + mt * 16 + quad * 4;
            size_t base = (size_t)mRow * ND + nBase + nt * 16 + col;
#pragma unroll
            for (int r = 0; r < 4; ++r) {
                out[base + (size_t)r * ND] = acc[mt][nt][r] + bias;
            }
        }
    }
}

extern "C" void kernel_launch(void* const* d_in, const int* in_sizes, int n_in,
                              void* d_out, int out_size, void* d_ws, size_t ws_size,
                              hipStream_t stream) {
    const float* tok  = (const float*)d_in[0];
    const int*   mask = (const int*)d_in[1];   // layout auto-detected in-kernel
    const float* W1   = (const float*)d_in[2];
    const float* b1   = (const float*)d_in[3];
    const float* W2   = (const float*)d_in[4];
    const float* b2   = (const float*)d_in[5];
    float*       out  = (float*)d_out;

    unsigned short* W2t = (unsigned short*)d_ws;                // 64 KB
    float4*         Pg  = (float4*)((char*)d_ws + 0x10000);     // 512 KB

    prep_kernel<<<dim3((ND * NH + NB * NT) / 256), dim3(256), 0, stream>>>(
        tok, mask, W2, W2t, Pg);

    dim3 gB(NT / 64, NB);
    fused_topk_mass_mlp_kernel<<<gB, dim3(512), 0, stream>>>(
        mask, W1, b1, W2t, b2, Pg, out);
}

// Round 5
// 144.714 us; speedup vs baseline: 1.2777x; 1.2777x over previous
//
#include <hip/hip_runtime.h>
#include <hip/hip_bf16.h>
#include <math.h>

#define NB 16
#define NT 2048
#define ND 512
#define NH 64

typedef __attribute__((ext_vector_type(8))) short short8;
typedef __attribute__((ext_vector_type(4))) float float4v;

// ---------------------------------------------------------------------------
// mask dtype robustness: byte layout -> first int32 reads 0x01010101 (lengths
// >= T/2 so mask[0..3] all true); int32 layout -> 1; f32 layout -> 0x3F800000.
// ---------------------------------------------------------------------------
__device__ __forceinline__ bool mask_is_bytes(const int* m) {
    return m[0] == 0x01010101;
}
__device__ __forceinline__ bool mask_at(const int* m, bool bytes, int i) {
    if (bytes) return ((const unsigned char*)m)[i] != 0;
    return m[i] != 0;
}

// Minkowski dot, metric folded into `a`; explicit fmaf so pass 1 / pass 2
// recompute bitwise-identical values.
__device__ __forceinline__ float dot4(float4 a, float4 p) {
    float d = a.x * p.x;
    d = __builtin_fmaf(a.y, p.y, d);
    d = __builtin_fmaf(a.z, p.z, d);
    d = __builtin_fmaf(a.w, p.w, d);
    return d;
}

__device__ __forceinline__ unsigned short f2bf(float x) {
    unsigned int u = __float_as_uint(x);
    u += 0x7fffu + ((u >> 16) & 1u);
    return (unsigned short)(u >> 16);
}

// sorted-desc top-8 insert chain (1 fmax + 7 med3)
#define CHAIN8(v0,v1,v2,v3,v4,v5,v6,v7,d) do {                 \
    float n0 = fmaxf(v0, d);                                    \
    float n1 = __builtin_amdgcn_fmed3f(d, v0, v1);              \
    float n2 = __builtin_amdgcn_fmed3f(d, v1, v2);              \
    float n3 = __builtin_amdgcn_fmed3f(d, v2, v3);              \
    float n4 = __builtin_amdgcn_fmed3f(d, v3, v4);              \
    float n5 = __builtin_amdgcn_fmed3f(d, v4, v5);              \
    float n6 = __builtin_amdgcn_fmed3f(d, v5, v6);              \
    float n7 = __builtin_amdgcn_fmed3f(d, v6, v7);              \
    v0 = n0; v1 = n1; v2 = n2; v3 = n3;                         \
    v4 = n4; v5 = n5; v6 = n6; v7 = n7;                         \
} while (0)

// ---------------------------------------------------------------------------
// Kernel A (prep): blocks [0,128) transpose W2 fp32[k][n] -> bf16 W2t[n][k];
// blocks [128,256) compute P (E,px,py,pz) per token once per batch into Pg.
// Masked tokens get sentinel (-1e30,0,0,0).
// ---------------------------------------------------------------------------
__global__ void __launch_bounds__(256) prep_kernel(
        const float* __restrict__ tok, const int* __restrict__ mask,
        const float* __restrict__ W2, unsigned short* __restrict__ W2t,
        float4* __restrict__ Pg) {
    int i = blockIdx.x * 256 + threadIdx.x;
    if (i < ND * NH) {
        int n = i & (ND - 1), k = i >> 9;
        W2t[n * NH + k] = f2bf(W2[k * ND + n]);
    } else {
        int j = i - ND * NH;                    // 0 .. NB*NT-1
        const bool mb = mask_is_bytes(mask);
        float4 tv = ((const float4*)tok)[j];
        bool m = mask_at(mask, mb, j);
        float E = tv.x, Pt = tv.y, eta = tv.z, phi = tv.w;
        float px = Pt * cosf(phi);
        float py = Pt * sinf(phi);
        float pz = Pt * sinhf(fminf(fmaxf(eta, -20.f), 20.f));
        Pg[j] = m ? make_float4(E, px, py, pz)
                  : make_float4(-1e30f, 0.f, 0.f, 0.f);
    }
}

// ---------------------------------------------------------------------------
// Kernel B: R0 structure (lane=query, LDS broadcast candidates) but each
// block serves TWO 64-token query tiles per candidate read: tileA = 64*x
// (always fully valid, since L >= 1024) and tileB = 1024 + 64*x (validity
// block-uniform / per-lane masked at mass). One ds_read_b128 feeds 128
// chains -> LDS pipe cost per query halves.
// LDS regions aliased: [Plds 32K (-> hs/mass after B4) | VT 32K -> PS 48K]
// = 80 KB, 1 block/CU. Grid: (NT/128, NB) = (16,16) = 256 blocks.
// ---------------------------------------------------------------------------
#define VTA(w2, j, l)  scratch[((w2) * 8 + (j)) * 64 + (l)]
#define VTB(w2, j, l)  scratch[4096 + ((w2) * 8 + (j)) * 64 + (l)]
#define PSA(w2, c, l)  scratch[((w2) * 12 + (c)) * 64 + (l)]
#define PSB(w2, c, l)  scratch[6144 + ((w2) * 12 + (c)) * 64 + (l)]

__global__ void __launch_bounds__(512) fused_topk_mass_mlp_kernel(
        const int* __restrict__ mask,
        const float* __restrict__ W1,
        const float* __restrict__ b1,
        const unsigned short* __restrict__ W2t,
        const float* __restrict__ b2,
        const float4* __restrict__ Pg,
        float* __restrict__ out) {
    // 32 KB Plds (later aliased by hs + mass_s) + 48 KB scratch (VT then PS)
    __shared__ __align__(16) unsigned char smem_raw[32768 + 49152];
    __shared__ int wcnt[8];
    float* Plds            = (float*)smem_raw;
    float* scratch         = (float*)(smem_raw + 32768);
    unsigned short (*hs)[88] = (unsigned short(*)[88])smem_raw;      // alias Plds
    float (*mass_s)[128]   = (float(*)[128])(smem_raw + 12288);      // alias Plds

    const int b    = blockIdx.y;
    const int x    = blockIdx.x;           // 0..15
    const int tA   = 64 * x;               // tokens 0..1023  (always < L)
    const int tB   = 1024 + 64 * x;        // tokens 1024..2047
    const int tid  = threadIdx.x;
    const int lane = tid & 63;
    const int w    = tid >> 6;
    const bool mb  = mask_is_bytes(mask);
    const float NEGBIG = -3.402823466e38f;
    const float MZ = sqrtf(1e-8f);

    // ---- stage Pg -> Plds; count L via ballots ----
    int cnt = 0;
    const float4* __restrict__ Pb = Pg + (size_t)b * NT;
#pragma unroll
    for (int it = 0; it < 4; ++it) {
        int i = tid + it * 512;
        *(float4*)&Plds[i * 4] = Pb[i];
        cnt += (int)__popcll(__ballot(mask_at(mask, mb, b * NT + i)));
    }
    if (lane == 0) wcnt[w] = cnt;
    __syncthreads();                               // B1

    int L = 0;
#pragma unroll
    for (int j = 0; j < 8; ++j) L += wcnt[j];
    const int C    = (L + 7) >> 3;
    const int sBeg = w * C;
    const int sEnd = min(sBeg + C, L);
    const bool hasB = tB < L;                      // block-uniform

    float4 pA = *(const float4*)&Plds[(tA + lane) * 4];
    float4 pBq = *(const float4*)&Plds[(tB + lane) * 4];
    float4 aA = make_float4(pA.x, -pA.y, -pA.z, -pA.w);
    float4 aB = make_float4(pBq.x, -pBq.y, -pBq.z, -pBq.w);

    float vA0 = NEGBIG, vA1 = NEGBIG, vA2 = NEGBIG, vA3 = NEGBIG;
    float vA4 = NEGBIG, vA5 = NEGBIG, vA6 = NEGBIG, vA7 = NEGBIG;
    float vB0 = NEGBIG, vB1 = NEGBIG, vB2 = NEGBIG, vB3 = NEGBIG;
    float vB4 = NEGBIG, vB5 = NEGBIG, vB6 = NEGBIG, vB7 = NEGBIG;

    // ---- pass 1: chunk-local top-8 for both query tiles per read ----
    if (hasB) {
#pragma unroll 4
        for (int s = sBeg; s < sEnd; ++s) {
            float4 ps = *(const float4*)&Plds[s * 4];
            float dA = dot4(aA, ps);
            float dB = dot4(aB, ps);
            CHAIN8(vA0, vA1, vA2, vA3, vA4, vA5, vA6, vA7, dA);
            CHAIN8(vB0, vB1, vB2, vB3, vB4, vB5, vB6, vB7, dB);
        }
    } else {
#pragma unroll 4
        for (int s = sBeg; s < sEnd; ++s) {
            float4 ps = *(const float4*)&Plds[s * 4];
            float dA = dot4(aA, ps);
            CHAIN8(vA0, vA1, vA2, vA3, vA4, vA5, vA6, vA7, dA);
        }
    }
    VTA(w, 0, lane) = vA0; VTA(w, 1, lane) = vA1;
    VTA(w, 2, lane) = vA2; VTA(w, 3, lane) = vA3;
    VTA(w, 4, lane) = vA4; VTA(w, 5, lane) = vA5;
    VTA(w, 6, lane) = vA6; VTA(w, 7, lane) = vA7;
    if (hasB) {
        VTB(w, 0, lane) = vB0; VTB(w, 1, lane) = vB1;
        VTB(w, 2, lane) = vB2; VTB(w, 3, lane) = vB3;
        VTB(w, 4, lane) = vB4; VTB(w, 5, lane) = vB5;
        VTB(w, 6, lane) = vB6; VTB(w, 7, lane) = vB7;
    }
    __syncthreads();                               // B2

    // ---- merge 64 candidates per query-set (redundant per wave) ----
    float thA2, thA4, thA8;
    {
        float m0 = NEGBIG, m1 = NEGBIG, m2_ = NEGBIG, m3 = NEGBIG;
        float m4 = NEGBIG, m5 = NEGBIG, m6 = NEGBIG, m7 = NEGBIG;
#pragma unroll
        for (int w2 = 0; w2 < 8; ++w2)
#pragma unroll
            for (int j = 0; j < 8; ++j) {
                float d = VTA(w2, j, lane);
                CHAIN8(m0, m1, m2_, m3, m4, m5, m6, m7, d);
            }
        thA2 = m1; thA4 = m3; thA8 = m7;
    }
    float thB2 = 0.f, thB4 = 0.f, thB8 = 0.f;
    if (hasB) {
        float m0 = NEGBIG, m1 = NEGBIG, m2_ = NEGBIG, m3 = NEGBIG;
        float m4 = NEGBIG, m5 = NEGBIG, m6 = NEGBIG, m7 = NEGBIG;
#pragma unroll
        for (int w2 = 0; w2 < 8; ++w2)
#pragma unroll
            for (int j = 0; j < 8; ++j) {
                float d = VTB(w2, j, lane);
                CHAIN8(m0, m1, m2_, m3, m4, m5, m6, m7, d);
            }
        thB2 = m1; thB4 = m3; thB8 = m7;
    }
    __syncthreads();                               // B3 (VT dead)

    // ---- pass 2: exact-membership partial sums (shared reads) ----
    {
        float a2x = 0.f, a2y = 0.f, a2z = 0.f, a2w = 0.f;
        float a4x = 0.f, a4y = 0.f, a4z = 0.f, a4w = 0.f;
        float a8x = 0.f, a8y = 0.f, a8z = 0.f, a8w = 0.f;
        float b2x = 0.f, b2y = 0.f, b2z = 0.f, b2w = 0.f;
        float b4x = 0.f, b4y = 0.f, b4z = 0.f, b4w = 0.f;
        float b8x = 0.f, b8y = 0.f, b8z = 0.f, b8w = 0.f;
        if (hasB) {
#pragma unroll 4
            for (int s = sBeg; s < sEnd; ++s) {
                float4 ps = *(const float4*)&Plds[s * 4];
                float dA = dot4(aA, ps);
                float dB = dot4(aB, ps);
                if (dA >= thA8) {
                    a8x += ps.x; a8y += ps.y; a8z += ps.z; a8w += ps.w;
                    if (dA >= thA4) {
                        a4x += ps.x; a4y += ps.y; a4z += ps.z; a4w += ps.w;
                        if (dA >= thA2) {
                            a2x += ps.x; a2y += ps.y; a2z += ps.z; a2w += ps.w;
                        }
                    }
                }
                if (dB >= thB8) {
                    b8x += ps.x; b8y += ps.y; b8z += ps.z; b8w += ps.w;
                    if (dB >= thB4) {
                        b4x += ps.x; b4y += ps.y; b4z += ps.z; b4w += ps.w;
                        if (dB >= thB2) {
                            b2x += ps.x; b2y += ps.y; b2z += ps.z; b2w += ps.w;
                        }
                    }
                }
            }
        } else {
#pragma unroll 4
            for (int s = sBeg; s < sEnd; ++s) {
                float4 ps = *(const float4*)&Plds[s * 4];
                float dA = dot4(aA, ps);
                if (dA >= thA8) {
                    a8x += ps.x; a8y += ps.y; a8z += ps.z; a8w += ps.w;
                    if (dA >= thA4) {
                        a4x += ps.x; a4y += ps.y; a4z += ps.z; a4w += ps.w;
                        if (dA >= thA2) {
                            a2x += ps.x; a2y += ps.y; a2z += ps.z; a2w += ps.w;
                        }
                    }
                }
            }
        }
        PSA(w, 0, lane) = a2x;  PSA(w, 1, lane) = a2y;
        PSA(w, 2, lane) = a2z;  PSA(w, 3, lane) = a2w;
        PSA(w, 4, lane) = a4x;  PSA(w, 5, lane) = a4y;
        PSA(w, 6, lane) = a4z;  PSA(w, 7, lane) = a4w;
        PSA(w, 8, lane) = a8x;  PSA(w, 9, lane) = a8y;
        PSA(w, 10, lane) = a8z; PSA(w, 11, lane) = a8w;
        if (hasB) {
            PSB(w, 0, lane) = b2x;  PSB(w, 1, lane) = b2y;
            PSB(w, 2, lane) = b2z;  PSB(w, 3, lane) = b2w;
            PSB(w, 4, lane) = b4x;  PSB(w, 5, lane) = b4y;
            PSB(w, 6, lane) = b4z;  PSB(w, 7, lane) = b4w;
            PSB(w, 8, lane) = b8x;  PSB(w, 9, lane) = b8y;
            PSB(w, 10, lane) = b8z; PSB(w, 11, lane) = b8w;
        }
    }
    __syncthreads();                               // B4 (Plds dead)

    // ---- waves 0/1: reduce + masses (mass_s aliases old Plds space) ----
    {
        auto massf = [](float sx, float sy, float sz, float sw) -> float {
            float q = sx * sx;
            q = __builtin_fmaf(-sy, sy, q);
            q = __builtin_fmaf(-sz, sz, q);
            q = __builtin_fmaf(-sw, sw, q);
            q = fmaxf(q, 0.f);
            return sqrtf(q + 1e-8f);
        };
        if (w == 0) {
            float tot[12];
#pragma unroll
            for (int c = 0; c < 12; ++c) {
                float acc = 0.f;
#pragma unroll
                for (int w2 = 0; w2 < 8; ++w2) acc += PSA(w2, c, lane);
                tot[c] = acc;
            }
            // tileA tokens (< 1024 <= L) are always valid
            mass_s[0][lane] = massf(tot[0], tot[1], tot[2], tot[3]);
            mass_s[1][lane] = massf(tot[4], tot[5], tot[6], tot[7]);
            mass_s[2][lane] = massf(tot[8], tot[9], tot[10], tot[11]);
        } else if (w == 1) {
            if (hasB) {
                float tot[12];
#pragma unroll
                for (int c = 0; c < 12; ++c) {
                    float acc = 0.f;
#pragma unroll
                    for (int w2 = 0; w2 < 8; ++w2) acc += PSB(w2, c, lane);
                    tot[c] = acc;
                }
                const bool maskt = (tB + lane) < L;   // mask monotone
                mass_s[0][64 + lane] = maskt ? massf(tot[0], tot[1], tot[2], tot[3]) : MZ;
                mass_s[1][64 + lane] = maskt ? massf(tot[4], tot[5], tot[6], tot[7]) : MZ;
                mass_s[2][64 + lane] = maskt ? massf(tot[8], tot[9], tot[10], tot[11]) : MZ;
            } else {
                mass_s[0][64 + lane] = MZ;
                mass_s[1][64 + lane] = MZ;
                mass_s[2][64 + lane] = MZ;
            }
        }
    }
    __syncthreads();                               // B5

    // ---- per output tile: MLP -> hs, then MFMA 64x512 + store ----
    const int col   = lane & 15;
    const int quad  = lane >> 4;
    const int mhalf = w >> 2;              // token half within tile (0..1)
    const int nBase = (w & 3) * 128;

#pragma unroll 1
    for (int m = 0; m < 2; ++m) {
        if (m) __syncthreads();            // hs reads of m=0 done before rewrite

        // h = gelu(mass @ W1 + b1), bf16 -> hs
        {
            float q0 = mass_s[0][m * 64 + lane];
            float q1 = mass_s[1][m * 64 + lane];
            float q2 = mass_s[2][m * 64 + lane];
            unsigned short hv[8];
#pragma unroll
            for (int j = 0; j < 8; ++j) {
                int hh = w * 8 + j;
                float pre = b1[hh];
                pre = __builtin_fmaf(q0, W1[hh], pre);
                pre = __builtin_fmaf(q1, W1[NH + hh], pre);
                pre = __builtin_fmaf(q2, W1[2 * NH + hh], pre);
                float g = 0.5f * pre * (1.0f + erff(pre * 0.70710678118654752f));
                hv[j] = f2bf(g);
            }
            *(short8*)&hs[lane][w * 8] = *(const short8*)hv;
        }
        __syncthreads();                           // B6

        short8 afrag[2][2];
#pragma unroll
        for (int mt = 0; mt < 2; ++mt)
#pragma unroll
            for (int ks = 0; ks < 2; ++ks)
                afrag[mt][ks] = *(const short8*)&hs[mhalf * 32 + mt * 16 + col][ks * 32 + quad * 8];

        float4v acc[2][8];
#pragma unroll
        for (int mt = 0; mt < 2; ++mt)
#pragma unroll
            for (int nt = 0; nt < 8; ++nt)
                acc[mt][nt] = (float4v)(0.f);

#pragma unroll
        for (int nt = 0; nt < 8; ++nt) {
            const unsigned short* wp = W2t + (nBase + nt * 16 + col) * NH + quad * 8;
            short8 bf0 = *(const short8*)(wp);
            short8 bf1 = *(const short8*)(wp + 32);
            acc[0][nt] = __builtin_amdgcn_mfma_f32_16x16x32_bf16(afrag[0][0], bf0, acc[0][nt], 0, 0, 0);
            acc[1][nt] = __builtin_amdgcn_mfma_f32_16x16x32_bf16(afrag[1][0], bf0, acc[1][nt], 0, 0, 0);
            acc[0][nt] = __builtin_amdgcn_mfma_f32_16x16x32_bf16(afrag[0][1], bf1, acc[0][nt], 0, 0, 0);
            acc[1][nt] = __builtin_amdgcn_mfma_f32_16x16x32_bf16(afrag[1][1], bf1, acc[1][nt], 0, 0, 0);
        }

        const int tileBase = b * NT + (m ? tB : tA);
#pragma unroll
        for (int nt = 0; nt < 8; ++nt) {
            float bias = b2[nBase + nt * 16 + col];
#pragma unroll
            for (int mt = 0; mt < 2; ++mt) {
                int mRow = tileBase + mhalf * 32 + mt * 16 + quad * 4;
                size_t base = (size_t)mRow * ND + nBase + nt * 16 + col;
#pragma unroll
                for (int r = 0; r < 4; ++r) {
                    out[base + (size_t)r * ND] = acc[mt][nt][r] + bias;
                }
            }
        }
    }
}

extern "C" void kernel_launch(void* const* d_in, const int* in_sizes, int n_in,
                              void* d_out, int out_size, void* d_ws, size_t ws_size,
                              hipStream_t stream) {
    const float* tok  = (const float*)d_in[0];
    const int*   mask = (const int*)d_in[1];   // layout auto-detected in-kernel
    const float* W1   = (const float*)d_in[2];
    const float* b1   = (const float*)d_in[3];
    const float* W2   = (const float*)d_in[4];
    const float* b2   = (const float*)d_in[5];
    float*       out  = (float*)d_out;

    unsigned short* W2t = (unsigned short*)d_ws;                // 64 KB
    float4*         Pg  = (float4*)((char*)d_ws + 0x10000);     // 512 KB

    prep_kernel<<<dim3((ND * NH + NB * NT) / 256), dim3(256), 0, stream>>>(
        tok, mask, W2, W2t, Pg);

    dim3 gB(NT / 128, NB);
    fused_topk_mass_mlp_kernel<<<gB, dim3(512), 0, stream>>>(
        mask, W1, b1, W2t, b2, Pg, out);
}

// Round 6
// 137.685 us; speedup vs baseline: 1.3430x; 1.0511x over previous
//
#include <hip/hip_runtime.h>
#include <hip/hip_bf16.h>
#include <math.h>

#define NB 16
#define NT 2048
#define ND 512
#define NH 64
#define NW 16   // waves per block

typedef __attribute__((ext_vector_type(8))) short short8;
typedef __attribute__((ext_vector_type(4))) float float4v;

// ---------------------------------------------------------------------------
// mask dtype robustness: byte layout -> first int32 reads 0x01010101 (lengths
// >= T/2 so mask[0..3] all true); int32 layout -> 1; f32 layout -> 0x3F800000.
// ---------------------------------------------------------------------------
__device__ __forceinline__ bool mask_is_bytes(const int* m) {
    return m[0] == 0x01010101;
}
__device__ __forceinline__ bool mask_at(const int* m, bool bytes, int i) {
    if (bytes) return ((const unsigned char*)m)[i] != 0;
    return m[i] != 0;
}

// Minkowski dot, metric folded into `a`; explicit fmaf so pass 1 / pass 2
// recompute bitwise-identical values.
__device__ __forceinline__ float dot4(float4 a, float4 p) {
    float d = a.x * p.x;
    d = __builtin_fmaf(a.y, p.y, d);
    d = __builtin_fmaf(a.z, p.z, d);
    d = __builtin_fmaf(a.w, p.w, d);
    return d;
}

__device__ __forceinline__ unsigned short f2bf(float x) {
    unsigned int u = __float_as_uint(x);
    u += 0x7fffu + ((u >> 16) & 1u);
    return (unsigned short)(u >> 16);
}

// sorted-desc top-8 insert chain (1 fmax + 7 med3)
#define CHAIN8(v0,v1,v2,v3,v4,v5,v6,v7,d) do {                 \
    float n0 = fmaxf(v0, d);                                    \
    float n1 = __builtin_amdgcn_fmed3f(d, v0, v1);              \
    float n2 = __builtin_amdgcn_fmed3f(d, v1, v2);              \
    float n3 = __builtin_amdgcn_fmed3f(d, v2, v3);              \
    float n4 = __builtin_amdgcn_fmed3f(d, v3, v4);              \
    float n5 = __builtin_amdgcn_fmed3f(d, v4, v5);              \
    float n6 = __builtin_amdgcn_fmed3f(d, v5, v6);              \
    float n7 = __builtin_amdgcn_fmed3f(d, v6, v7);              \
    v0 = n0; v1 = n1; v2 = n2; v3 = n3;                         \
    v4 = n4; v5 = n5; v6 = n6; v7 = n7;                         \
} while (0)

// ---------------------------------------------------------------------------
// Kernel A (prep): blocks [0,128) transpose W2 fp32[k][n] -> bf16 W2t[n][k];
// blocks [128,256) compute P (E,px,py,pz) per token once per batch into Pg.
// Masked tokens get sentinel (-1e30,0,0,0).
// ---------------------------------------------------------------------------
__global__ void __launch_bounds__(256) prep_kernel(
        const float* __restrict__ tok, const int* __restrict__ mask,
        const float* __restrict__ W2, unsigned short* __restrict__ W2t,
        float4* __restrict__ Pg) {
    int i = blockIdx.x * 256 + threadIdx.x;
    if (i < ND * NH) {
        int n = i & (ND - 1), k = i >> 9;
        W2t[n * NH + k] = f2bf(W2[k * ND + n]);
    } else {
        int j = i - ND * NH;                    // 0 .. NB*NT-1
        const bool mb = mask_is_bytes(mask);
        float4 tv = ((const float4*)tok)[j];
        bool m = mask_at(mask, mb, j);
        float E = tv.x, Pt = tv.y, eta = tv.z, phi = tv.w;
        float px = Pt * cosf(phi);
        float py = Pt * sinf(phi);
        float pz = Pt * sinhf(fminf(fmaxf(eta, -20.f), 20.f));
        Pg[j] = m ? make_float4(E, px, py, pz)
                  : make_float4(-1e30f, 0.f, 0.f, 0.f);
    }
}

// ---------------------------------------------------------------------------
// Kernel B: 2-tile amortized scan (R5) at 16 waves / 1024 threads (R6).
// 256 blocks = 1/CU, but now 4 waves/SIMD for latency hiding.
// Phases: stage+count | pass1 (both tiles per read) | waves 0/1 merge ->
// thresholds in LDS | pass2 | waves 0/1 reduce -> mass | parallel epilogue
// (waves 0-7 tile A, 8-15 tile B: MLP -> hs -> MFMA -> store).
// LDS (floats): [0,8192) Plds (-> hsA/hsB/mass after B4)
//               [8192,16384) VTA   [16384,24576) VTB
//               PSA [8192,20480)  PSB [20480,32768)  (alias dead VT)
// Total 128 KB + thS/wcnt. 1 block/CU.
// ---------------------------------------------------------------------------
#define VTA(w2, j, l)  S[ 8192 + ((w2) * 8 + (j)) * 64 + (l)]
#define VTB(w2, j, l)  S[16384 + ((w2) * 8 + (j)) * 64 + (l)]
#define PSA(w2, c, l)  S[ 8192 + ((w2) * 12 + (c)) * 64 + (l)]
#define PSB(w2, c, l)  S[20480 + ((w2) * 12 + (c)) * 64 + (l)]

__global__ void __launch_bounds__(1024) fused_topk_mass_mlp_kernel(
        const int* __restrict__ mask,
        const float* __restrict__ W1,
        const float* __restrict__ b1,
        const unsigned short* __restrict__ W2t,
        const float* __restrict__ b2,
        const float4* __restrict__ Pg,
        float* __restrict__ out) {
    __shared__ __align__(16) float S[32768];   // 128 KB
    __shared__ float thS[6][64];               // thA2/4/8, thB2/4/8
    __shared__ int wcnt[NW];

    float* Plds = S;
    unsigned short (*hsA)[88] = (unsigned short(*)[88])S;            // 2816 fl
    unsigned short (*hsB)[88] = (unsigned short(*)[88])(S + 2816);   // 2816 fl
    float (*mass_s)[128]      = (float(*)[128])(S + 5632);           // 384 fl

    const int b    = blockIdx.y;
    const int x    = blockIdx.x;           // 0..15
    const int tA   = 64 * x;               // tokens 0..1023 (always < L)
    const int tB   = 1024 + 64 * x;        // tokens 1024..2047
    const int tid  = threadIdx.x;
    const int lane = tid & 63;
    const int w    = tid >> 6;             // 0..15
    const bool mb  = mask_is_bytes(mask);
    const float NEGBIG = -3.402823466e38f;
    const float MZ = sqrtf(1e-8f);

    // ---- stage Pg -> Plds; count L via ballots ----
    int cnt = 0;
    const float4* __restrict__ Pb = Pg + (size_t)b * NT;
#pragma unroll
    for (int it = 0; it < 2; ++it) {
        int i = tid + it * 1024;
        *(float4*)&Plds[i * 4] = Pb[i];
        cnt += (int)__popcll(__ballot(mask_at(mask, mb, b * NT + i)));
    }
    if (lane == 0) wcnt[w] = cnt;
    __syncthreads();                               // B1

    int L = 0;
#pragma unroll
    for (int j = 0; j < NW; ++j) L += wcnt[j];
    const int C    = (L + NW - 1) / NW;
    const int sBeg = w * C;
    const int sEnd = min(sBeg + C, L);
    const bool hasB = tB < L;                      // block-uniform

    float4 pA  = *(const float4*)&Plds[(tA + lane) * 4];
    float4 pBq = *(const float4*)&Plds[(tB + lane) * 4];
    float4 aA = make_float4(pA.x, -pA.y, -pA.z, -pA.w);
    float4 aB = make_float4(pBq.x, -pBq.y, -pBq.z, -pBq.w);

    float vA0 = NEGBIG, vA1 = NEGBIG, vA2 = NEGBIG, vA3 = NEGBIG;
    float vA4 = NEGBIG, vA5 = NEGBIG, vA6 = NEGBIG, vA7 = NEGBIG;
    float vB0 = NEGBIG, vB1 = NEGBIG, vB2 = NEGBIG, vB3 = NEGBIG;
    float vB4 = NEGBIG, vB5 = NEGBIG, vB6 = NEGBIG, vB7 = NEGBIG;

    // ---- pass 1: chunk-local top-8 for both query tiles per read ----
    if (hasB) {
#pragma unroll 4
        for (int s = sBeg; s < sEnd; ++s) {
            float4 ps = *(const float4*)&Plds[s * 4];
            float dA = dot4(aA, ps);
            float dB = dot4(aB, ps);
            CHAIN8(vA0, vA1, vA2, vA3, vA4, vA5, vA6, vA7, dA);
            CHAIN8(vB0, vB1, vB2, vB3, vB4, vB5, vB6, vB7, dB);
        }
    } else {
#pragma unroll 4
        for (int s = sBeg; s < sEnd; ++s) {
            float4 ps = *(const float4*)&Plds[s * 4];
            float dA = dot4(aA, ps);
            CHAIN8(vA0, vA1, vA2, vA3, vA4, vA5, vA6, vA7, dA);
        }
    }
    VTA(w, 0, lane) = vA0; VTA(w, 1, lane) = vA1;
    VTA(w, 2, lane) = vA2; VTA(w, 3, lane) = vA3;
    VTA(w, 4, lane) = vA4; VTA(w, 5, lane) = vA5;
    VTA(w, 6, lane) = vA6; VTA(w, 7, lane) = vA7;
    if (hasB) {
        VTB(w, 0, lane) = vB0; VTB(w, 1, lane) = vB1;
        VTB(w, 2, lane) = vB2; VTB(w, 3, lane) = vB3;
        VTB(w, 4, lane) = vB4; VTB(w, 5, lane) = vB5;
        VTB(w, 6, lane) = vB6; VTB(w, 7, lane) = vB7;
    }
    __syncthreads();                               // B2

    // ---- dedicated merge: wave 0 merges A, wave 1 merges B ----
    if (w == 0) {
        float m0 = NEGBIG, m1 = NEGBIG, m2_ = NEGBIG, m3 = NEGBIG;
        float m4 = NEGBIG, m5 = NEGBIG, m6 = NEGBIG, m7 = NEGBIG;
#pragma unroll
        for (int w2 = 0; w2 < NW; ++w2)
#pragma unroll
            for (int j = 0; j < 8; ++j) {
                float d = VTA(w2, j, lane);
                CHAIN8(m0, m1, m2_, m3, m4, m5, m6, m7, d);
            }
        thS[0][lane] = m1; thS[1][lane] = m3; thS[2][lane] = m7;
    } else if (w == 1 && hasB) {
        float m0 = NEGBIG, m1 = NEGBIG, m2_ = NEGBIG, m3 = NEGBIG;
        float m4 = NEGBIG, m5 = NEGBIG, m6 = NEGBIG, m7 = NEGBIG;
#pragma unroll
        for (int w2 = 0; w2 < NW; ++w2)
#pragma unroll
            for (int j = 0; j < 8; ++j) {
                float d = VTB(w2, j, lane);
                CHAIN8(m0, m1, m2_, m3, m4, m5, m6, m7, d);
            }
        thS[3][lane] = m1; thS[4][lane] = m3; thS[5][lane] = m7;
    }
    __syncthreads();                               // B3 (VT dead)

    const float thA2 = thS[0][lane], thA4 = thS[1][lane], thA8 = thS[2][lane];
    const float thB2 = hasB ? thS[3][lane] : 0.f;
    const float thB4 = hasB ? thS[4][lane] : 0.f;
    const float thB8 = hasB ? thS[5][lane] : 0.f;

    // ---- pass 2: exact-membership partial sums (shared reads) ----
    {
        float a2x = 0.f, a2y = 0.f, a2z = 0.f, a2w = 0.f;
        float a4x = 0.f, a4y = 0.f, a4z = 0.f, a4w = 0.f;
        float a8x = 0.f, a8y = 0.f, a8z = 0.f, a8w = 0.f;
        float b2x = 0.f, b2y = 0.f, b2z = 0.f, b2w = 0.f;
        float b4x = 0.f, b4y = 0.f, b4z = 0.f, b4w = 0.f;
        float b8x = 0.f, b8y = 0.f, b8z = 0.f, b8w = 0.f;
        if (hasB) {
#pragma unroll 4
            for (int s = sBeg; s < sEnd; ++s) {
                float4 ps = *(const float4*)&Plds[s * 4];
                float dA = dot4(aA, ps);
                float dB = dot4(aB, ps);
                if (dA >= thA8) {
                    a8x += ps.x; a8y += ps.y; a8z += ps.z; a8w += ps.w;
                    if (dA >= thA4) {
                        a4x += ps.x; a4y += ps.y; a4z += ps.z; a4w += ps.w;
                        if (dA >= thA2) {
                            a2x += ps.x; a2y += ps.y; a2z += ps.z; a2w += ps.w;
                        }
                    }
                }
                if (dB >= thB8) {
                    b8x += ps.x; b8y += ps.y; b8z += ps.z; b8w += ps.w;
                    if (dB >= thB4) {
                        b4x += ps.x; b4y += ps.y; b4z += ps.z; b4w += ps.w;
                        if (dB >= thB2) {
                            b2x += ps.x; b2y += ps.y; b2z += ps.z; b2w += ps.w;
                        }
                    }
                }
            }
        } else {
#pragma unroll 4
            for (int s = sBeg; s < sEnd; ++s) {
                float4 ps = *(const float4*)&Plds[s * 4];
                float dA = dot4(aA, ps);
                if (dA >= thA8) {
                    a8x += ps.x; a8y += ps.y; a8z += ps.z; a8w += ps.w;
                    if (dA >= thA4) {
                        a4x += ps.x; a4y += ps.y; a4z += ps.z; a4w += ps.w;
                        if (dA >= thA2) {
                            a2x += ps.x; a2y += ps.y; a2z += ps.z; a2w += ps.w;
                        }
                    }
                }
            }
        }
        PSA(w, 0, lane) = a2x;  PSA(w, 1, lane) = a2y;
        PSA(w, 2, lane) = a2z;  PSA(w, 3, lane) = a2w;
        PSA(w, 4, lane) = a4x;  PSA(w, 5, lane) = a4y;
        PSA(w, 6, lane) = a4z;  PSA(w, 7, lane) = a4w;
        PSA(w, 8, lane) = a8x;  PSA(w, 9, lane) = a8y;
        PSA(w, 10, lane) = a8z; PSA(w, 11, lane) = a8w;
        if (hasB) {
            PSB(w, 0, lane) = b2x;  PSB(w, 1, lane) = b2y;
            PSB(w, 2, lane) = b2z;  PSB(w, 3, lane) = b2w;
            PSB(w, 4, lane) = b4x;  PSB(w, 5, lane) = b4y;
            PSB(w, 6, lane) = b4z;  PSB(w, 7, lane) = b4w;
            PSB(w, 8, lane) = b8x;  PSB(w, 9, lane) = b8y;
            PSB(w, 10, lane) = b8z; PSB(w, 11, lane) = b8w;
        }
    }
    __syncthreads();                               // B4 (Plds dead)

    // ---- waves 0/1: reduce + masses (mass_s aliases old Plds space) ----
    {
        auto massf = [](float sx, float sy, float sz, float sw) -> float {
            float q = sx * sx;
            q = __builtin_fmaf(-sy, sy, q);
            q = __builtin_fmaf(-sz, sz, q);
            q = __builtin_fmaf(-sw, sw, q);
            q = fmaxf(q, 0.f);
            return sqrtf(q + 1e-8f);
        };
        if (w == 0) {
            float tot[12];
#pragma unroll
            for (int c = 0; c < 12; ++c) {
                float acc = 0.f;
#pragma unroll
                for (int w2 = 0; w2 < NW; ++w2) acc += PSA(w2, c, lane);
                tot[c] = acc;
            }
            // tileA tokens (< 1024 <= L) are always valid
            mass_s[0][lane] = massf(tot[0], tot[1], tot[2], tot[3]);
            mass_s[1][lane] = massf(tot[4], tot[5], tot[6], tot[7]);
            mass_s[2][lane] = massf(tot[8], tot[9], tot[10], tot[11]);
        } else if (w == 1) {
            if (hasB) {
                float tot[12];
#pragma unroll
                for (int c = 0; c < 12; ++c) {
                    float acc = 0.f;
#pragma unroll
                    for (int w2 = 0; w2 < NW; ++w2) acc += PSB(w2, c, lane);
                    tot[c] = acc;
                }
                const bool maskt = (tB + lane) < L;   // mask monotone
                mass_s[0][64 + lane] = maskt ? massf(tot[0], tot[1], tot[2], tot[3]) : MZ;
                mass_s[1][64 + lane] = maskt ? massf(tot[4], tot[5], tot[6], tot[7]) : MZ;
                mass_s[2][64 + lane] = maskt ? massf(tot[8], tot[9], tot[10], tot[11]) : MZ;
            } else {
                mass_s[0][64 + lane] = MZ;
                mass_s[1][64 + lane] = MZ;
                mass_s[2][64 + lane] = MZ;
            }
        }
    }
    __syncthreads();                               // B5

    // ---- parallel epilogue: waves 0-7 tile A, waves 8-15 tile B ----
    const int m     = w >> 3;              // 0 = tileA, 1 = tileB
    const int wl    = w & 7;
    const int col   = lane & 15;
    const int quad  = lane >> 4;
    const int mhalf = wl >> 2;             // token half within tile
    const int nBase = (wl & 3) * 128;
    unsigned short (*hsm)[88] = m ? hsB : hsA;

    // h = gelu(mass @ W1 + b1), bf16 -> hs
    {
        float q0 = mass_s[0][m * 64 + lane];
        float q1 = mass_s[1][m * 64 + lane];
        float q2 = mass_s[2][m * 64 + lane];
        unsigned short hv[8];
#pragma unroll
        for (int j = 0; j < 8; ++j) {
            int hh = wl * 8 + j;
            float pre = b1[hh];
            pre = __builtin_fmaf(q0, W1[hh], pre);
            pre = __builtin_fmaf(q1, W1[NH + hh], pre);
            pre = __builtin_fmaf(q2, W1[2 * NH + hh], pre);
            float g = 0.5f * pre * (1.0f + erff(pre * 0.70710678118654752f));
            hv[j] = f2bf(g);
        }
        *(short8*)&hsm[lane][wl * 8] = *(const short8*)hv;
    }
    __syncthreads();                               // B6

    short8 afrag[2][2];
#pragma unroll
    for (int mt = 0; mt < 2; ++mt)
#pragma unroll
        for (int ks = 0; ks < 2; ++ks)
            afrag[mt][ks] = *(const short8*)&hsm[mhalf * 32 + mt * 16 + col][ks * 32 + quad * 8];

    float4v acc[2][8];
#pragma unroll
    for (int mt = 0; mt < 2; ++mt)
#pragma unroll
        for (int nt = 0; nt < 8; ++nt)
            acc[mt][nt] = (float4v)(0.f);

#pragma unroll
    for (int nt = 0; nt < 8; ++nt) {
        const unsigned short* wp = W2t + (nBase + nt * 16 + col) * NH + quad * 8;
        short8 bf0 = *(const short8*)(wp);
        short8 bf1 = *(const short8*)(wp + 32);
        acc[0][nt] = __builtin_amdgcn_mfma_f32_16x16x32_bf16(afrag[0][0], bf0, acc[0][nt], 0, 0, 0);
        acc[1][nt] = __builtin_amdgcn_mfma_f32_16x16x32_bf16(afrag[1][0], bf0, acc[1][nt], 0, 0, 0);
        acc[0][nt] = __builtin_amdgcn_mfma_f32_16x16x32_bf16(afrag[0][1], bf1, acc[0][nt], 0, 0, 0);
        acc[1][nt] = __builtin_amdgcn_mfma_f32_16x16x32_bf16(afrag[1][1], bf1, acc[1][nt], 0, 0, 0);
    }

    const int tileBase = b * NT + (m ? tB : tA);
#pragma unroll
    for (int nt = 0; nt < 8; ++nt) {
        float bias = b2[nBase + nt * 16 + col];
#pragma unroll
        for (int mt = 0; mt < 2; ++mt) {
            int mRow = tileBase + mhalf * 32 + mt * 16 + quad * 4;
            size_t base = (size_t)mRow * ND + nBase + nt * 16 + col;
#pragma unroll
            for (int r = 0; r < 4; ++r) {
                out[base + (size_t)r * ND] = acc[mt][nt][r] + bias;
            }
        }
    }
}

extern "C" void kernel_launch(void* const* d_in, const int* in_sizes, int n_in,
                              void* d_out, int out_size, void* d_ws, size_t ws_size,
                              hipStream_t stream) {
    const float* tok  = (const float*)d_in[0];
    const int*   mask = (const int*)d_in[1];   // layout auto-detected in-kernel
    const float* W1   = (const float*)d_in[2];
    const float* b1   = (const float*)d_in[3];
    const float* W2   = (const float*)d_in[4];
    const float* b2   = (const float*)d_in[5];
    float*       out  = (float*)d_out;

    unsigned short* W2t = (unsigned short*)d_ws;                // 64 KB
    float4*         Pg  = (float4*)((char*)d_ws + 0x10000);     // 512 KB

    prep_kernel<<<dim3((ND * NH + NB * NT) / 256), dim3(256), 0, stream>>>(
        tok, mask, W2, W2t, Pg);

    dim3 gB(NT / 128, NB);
    fused_topk_mass_mlp_kernel<<<gB, dim3(1024), 0, stream>>>(
        mask, W1, b1, W2t, b2, Pg, out);
}